// Round 13
// baseline (362.080 us; speedup 1.0000x reference)
//
#include <hip/hip_runtime.h>
#include <hip/hip_fp16.h>
#include <math.h>

#define HEADS 4
#define OUT_F 32
#define HF 128      // HEADS*OUT_F
#define IN_F 64
#define EDGE_F 16

typedef int   v4i __attribute__((ext_vector_type(4)));
typedef float v4f __attribute__((ext_vector_type(4)));
typedef float v2f __attribute__((ext_vector_type(2)));
typedef _Float16 v8h __attribute__((ext_vector_type(8)));

// ---------- R16: gather fast-path (all-chains-alive, unguarded) + predicated tail ----------
// R15 measured: branch-free 4-chain chase took gather 173->105us, VALUBusy 29->74%:
// now VALU-issue-bound. ~85% of iterations have all 4 chains alive (len ~ deg/4), yet
// every iteration paid ~16-20 VALU of clamp/mask overhead. Fast path: while
// (e0|e1|e2|e3)>=0 (OR of non-negatives is non-negative -> 1 op test) run an unguarded
// body; on first chain death fall into the predicated tail loop.

__global__ __launch_bounds__(256) void k_project_mfma(
    const float* __restrict__ x, const float* __restrict__ W_lin,
    const float* __restrict__ W_res, const float* __restrict__ bias,
    const float* __restrict__ w_s, const float* __restrict__ w_t,
    const float* __restrict__ b_s, const float* __restrict__ b_t,
    __half* __restrict__ xp, float* __restrict__ a_s, float* __restrict__ a_t,
    float* __restrict__ out, int* __restrict__ head, int N_, int PB) {
  if (blockIdx.x >= PB) {  // head-init block (was hipMemsetAsync)
    int i = (blockIdx.x - PB) * 256 + threadIdx.x;
    if (i < N_ * 4) head[i] = -1;
    return;
  }
  __shared__ __half sw[256][72];   // [outc 0..255][k], rows 0-127 = W_lin, 128-255 = W_res
  __shared__ __half sxh[64][72];   // [node][k]
  int t = threadIdx.x;
  // ---- stage weights (f32 -> f16) ----
  {
    const float* wsrc = (t < 128) ? (W_lin + t * IN_F) : (W_res + (size_t)(t - 128) * IN_F);
    const float4* w4 = (const float4*)wsrc;
#pragma unroll
    for (int k8 = 0; k8 < 8; k8++) {
      float4 f0 = w4[k8 * 2 + 0];
      float4 f1 = w4[k8 * 2 + 1];
      *(__half2*)(&sw[t][k8 * 8 + 0]) = __floats2half2_rn(f0.x, f0.y);
      *(__half2*)(&sw[t][k8 * 8 + 2]) = __floats2half2_rn(f0.z, f0.w);
      *(__half2*)(&sw[t][k8 * 8 + 4]) = __floats2half2_rn(f1.x, f1.y);
      *(__half2*)(&sw[t][k8 * 8 + 6]) = __floats2half2_rn(f1.z, f1.w);
    }
  }
  // ---- stage x tile (64 nodes, f32 -> f16) ----
  int n0 = blockIdx.x * 64;
  {
    int node = t >> 2, q = t & 3;        // 4 threads per node, 16 floats each
    int nn = n0 + node;
    const float4* xs = (const float4*)(x + (size_t)nn * IN_F) + q * 4;
#pragma unroll
    for (int j = 0; j < 4; j++) {
      float4 f = (nn < N_) ? xs[j] : make_float4(0.f, 0.f, 0.f, 0.f);
      int col = q * 16 + j * 4;
      *(__half2*)(&sxh[node][col + 0]) = __floats2half2_rn(f.x, f.y);
      *(__half2*)(&sxh[node][col + 2]) = __floats2half2_rn(f.z, f.w);
    }
  }
  __syncthreads();

  int w = t >> 6, l = t & 63;
  int lm = l & 15, lg = l >> 4;          // D: col=lm, row=lg*4+reg
  int mbase = n0 + w * 16;
  // A fragments for this wave's 16-node M-tile (row = lm, k = lg*8 + j)
  v8h a0 = *(const v8h*)(&sxh[w * 16 + lm][lg * 8]);
  v8h a1 = *(const v8h*)(&sxh[w * 16 + lm][32 + lg * 8]);

  float ws_lo = w_s[lm], ws_hi = w_s[16 + lm];
  float wt_lo = w_t[lm], wt_hi = w_t[16 + lm];
  float bsv = b_s[0], btv = b_t[0];

  float sacc[4] = {0.f, 0.f, 0.f, 0.f};
  float tacc[4] = {0.f, 0.f, 0.f, 0.f};

#pragma unroll
  for (int nt = 0; nt < 16; nt++) {
    // B fragment: col = nt*16+lm (row of sw), k = kb*32 + lg*8
    v8h b0 = *(const v8h*)(&sw[nt * 16 + lm][lg * 8]);
    v8h b1 = *(const v8h*)(&sw[nt * 16 + lm][32 + lg * 8]);
    v4f d = {0.f, 0.f, 0.f, 0.f};
    d = __builtin_amdgcn_mfma_f32_16x16x32_f16(a0, b0, d, 0, 0, 0);
    d = __builtin_amdgcn_mfma_f32_16x16x32_f16(a1, b1, d, 0, 0, 0);
    if (nt < 8) {
      // lin features c = nt*16+lm -> xp f16 + attention partials
      int c = nt * 16 + lm;
      float wssel = (nt & 1) ? ws_hi : ws_lo;
      float wtsel = (nt & 1) ? wt_hi : wt_lo;
#pragma unroll
      for (int reg = 0; reg < 4; reg++) {
        int m = mbase + lg * 4 + reg;
        if (m < N_) xp[(size_t)m * HF + c] = __float2half(d[reg]);
        sacc[reg] += d[reg] * wssel;
        tacc[reg] += d[reg] * wtsel;
      }
      if (nt & 1) {  // head h = nt>>1 complete: reduce over the 16-lane c-group
        int h = nt >> 1;
#pragma unroll
        for (int reg = 0; reg < 4; reg++) {
#pragma unroll
          for (int dlt = 8; dlt > 0; dlt >>= 1) {
            sacc[reg] += __shfl_xor(sacc[reg], dlt, 64);
            tacc[reg] += __shfl_xor(tacc[reg], dlt, 64);
          }
        }
        if (lm == 0) {
#pragma unroll
          for (int reg = 0; reg < 4; reg++) {
            int m = mbase + lg * 4 + reg;
            if (m < N_) {
              a_s[m * 4 + h] = sacc[reg] + bsv;
              a_t[m * 4 + h] = tacc[reg] + btv;
            }
          }
        }
#pragma unroll
        for (int reg = 0; reg < 4; reg++) { sacc[reg] = 0.f; tacc[reg] = 0.f; }
      }
    } else {
      // res features c = (nt-8)*16+lm -> out f32 + bias
      int c = (nt - 8) * 16 + lm;
      float bv = bias[c];
#pragma unroll
      for (int reg = 0; reg < 4; reg++) {
        int m = mbase + lg * 4 + reg;
        if (m < N_) out[(size_t)m * HF + c] = d[reg] + bv;
      }
    }
  }
}

// ---------- per-edge: logits + exp + chain push (atomicExch returns next) ----------
__global__ __launch_bounds__(256) void k_edge_logits(
    const int* __restrict__ ei, const float* __restrict__ ea,
    const float* __restrict__ W_edge, const float* __restrict__ w_e,
    const float* __restrict__ b_e,
    const float* __restrict__ a_s, const float* __restrict__ a_t,
    int* __restrict__ head, v4i* __restrict__ pay, int E_) {
  __shared__ float sv[64];
  {
    int t = threadIdx.x;
    if (t < 64) {  // fold W_edge (128x16) with w_e -> v_e[4][16], from L2
      int h = t >> 4, cc = t & 15;
      float se = 0.f;
#pragma unroll
      for (int f = 0; f < 32; f++) se += W_edge[(h * 32 + f) * 16 + cc] * w_e[f];
      sv[t] = se;
    }
  }
  __syncthreads();
  int e = blockIdx.x * 256 + threadIdx.x;
  if (e >= E_) return;
  int src = ei[e], dst = ei[E_ + e];
  // early atomic: old head IS the next pointer; consumed only by the final store,
  // so the round-trip hides under the streaming loads + logit math below.
  int nx = atomicExch(head + dst * 4 + (e & 3), e);
  float bev = b_e[0];
  const v4f* ea4 = (const v4f*)(ea + (size_t)e * EDGE_F);
  v4f e0 = __builtin_nontemporal_load(ea4 + 0);   // streamed: read-once
  v4f e1 = __builtin_nontemporal_load(ea4 + 1);
  v4f e2 = __builtin_nontemporal_load(ea4 + 2);
  v4f e3 = __builtin_nontemporal_load(ea4 + 3);
  float4 as4 = *(const float4*)(a_s + src * 4);   // random 16B, L2-resident (800KB)
  float4 at4 = *(const float4*)(a_t + dst * 4);
  float asv[4] = {as4.x, as4.y, as4.z, as4.w};
  float atv[4] = {at4.x, at4.y, at4.z, at4.w};
  float res[4];
#pragma unroll
  for (int h = 0; h < 4; h++) {
    const float* v = sv + h * 16;
    float ae =
        e0.x * v[0]  + e0.y * v[1]  + e0.z * v[2]  + e0.w * v[3]
      + e1.x * v[4]  + e1.y * v[5]  + e1.z * v[6]  + e1.w * v[7]
      + e2.x * v[8]  + e2.y * v[9]  + e2.z * v[10] + e2.w * v[11]
      + e3.x * v[12] + e3.y * v[13] + e3.z * v[14] + e3.w * v[15];
    float al = asv[h] + atv[h] + ae + bev;
    al = al >= 0.f ? al : 0.2f * al;
    res[h] = __expf(al);  // shift-free softmax: |alpha| is O(1)
  }
  __half2 h01 = __floats2half2_rn(res[0], res[1]);
  __half2 h23 = __floats2half2_rn(res[2], res[3]);
  v4i pk;
  pk.x = src;
  pk.y = *(int*)&h01;
  pk.z = *(int*)&h23;
  pk.w = nx;               // next pointer from the atomic -> 1 load/step in gather
  pay[e] = pk;             // COALESCED store
}

// ---------- gather: one wave per dst, 4 chains; fast path + predicated tail ----------
__global__ __launch_bounds__(256) void k_gather(
    const int* __restrict__ head, const v4i* __restrict__ pay,
    const __half* __restrict__ xp, float* __restrict__ out, int N_, int E_) {
  int wid = threadIdx.x >> 6, lane = threadIdx.x & 63;
  int n = blockIdx.x * 4 + wid;
  if (n >= N_) return;
  int e0 = head[n * 4 + 0], e1 = head[n * 4 + 1];
  int e2 = head[n * 4 + 2], e3 = head[n * 4 + 3];
  if ((e0 & e1 & e2 & e3) < 0 && e0 < 0 && e1 < 0 && e2 < 0 && e3 < 0)
    return;  // no in-edges: keep residual
  int h = lane >> 4;  // features 2*lane, 2*lane+1 -> head (2*lane)>>5 = lane>>4
  float2 acc = make_float2(0.f, 0.f);
  float se = 0.f;
#define EXTRACT_EV(P, EV)                                                \
  {                                                                      \
    unsigned hw = (h < 2) ? (unsigned)(P).y : (unsigned)(P).z;           \
    unsigned bits = (h & 1) ? (hw >> 16) : (hw & 0xffffu);               \
    EV = __half2float(__ushort_as_half((unsigned short)bits));           \
  }
#define ROW_FMA(P, EV)                                                   \
  {                                                                      \
    const __half2* xr = (const __half2*)(xp + (size_t)(P).x * HF);       \
    float2 xv = __half22float2(xr[lane]);                                \
    acc.x += (EV) * xv.x;                                                \
    acc.y += (EV) * xv.y;                                                \
    se += (EV);                                                          \
  }
  // ---- fast path: all 4 chains alive (OR of non-negatives is non-negative) ----
  while ((e0 | e1 | e2 | e3) >= 0) {
    v4i p0 = pay[e0];
    v4i p1 = pay[e1];
    v4i p2 = pay[e2];
    v4i p3 = pay[e3];
    float ev0, ev1, ev2, ev3;
    EXTRACT_EV(p0, ev0);
    EXTRACT_EV(p1, ev1);
    EXTRACT_EV(p2, ev2);
    EXTRACT_EV(p3, ev3);
    ROW_FMA(p0, ev0);
    ROW_FMA(p1, ev1);
    ROW_FMA(p2, ev2);
    ROW_FMA(p3, ev3);
    e0 = p0.w;
    e1 = p1.w;
    e2 = p2.w;
    e3 = p3.w;
  }
  // ---- tail: predicated (some chains dead) ----
  for (int it = 0; it < E_; ++it) {  // cap: inert on correct data
    if (e0 < 0 && e1 < 0 && e2 < 0 && e3 < 0) break;  // uniform
    int s0 = e0 < 0 ? 0 : e0, s1 = e1 < 0 ? 0 : e1;
    int s2 = e2 < 0 ? 0 : e2, s3 = e3 < 0 ? 0 : e3;
    v4i p0 = pay[s0];
    v4i p1 = pay[s1];
    v4i p2 = pay[s2];
    v4i p3 = pay[s3];
    float m0 = e0 < 0 ? 0.f : 1.f, m1 = e1 < 0 ? 0.f : 1.f;
    float m2 = e2 < 0 ? 0.f : 1.f, m3 = e3 < 0 ? 0.f : 1.f;
    float ev0, ev1, ev2, ev3;
    EXTRACT_EV(p0, ev0);
    EXTRACT_EV(p1, ev1);
    EXTRACT_EV(p2, ev2);
    EXTRACT_EV(p3, ev3);
    ev0 *= m0; ev1 *= m1; ev2 *= m2; ev3 *= m3;
    ROW_FMA(p0, ev0);
    ROW_FMA(p1, ev1);
    ROW_FMA(p2, ev2);
    ROW_FMA(p3, ev3);
    e0 = e0 < 0 ? e0 : p0.w;
    e1 = e1 < 0 ? e1 : p1.w;
    e2 = e2 < 0 ? e2 : p2.w;
    e3 = e3 < 0 ? e3 : p3.w;
  }
#undef EXTRACT_EV
#undef ROW_FMA
  float r = 1.f / se;  // se > 0: at least one edge processed, expv > 0
  size_t oi = (size_t)n * 64 + lane;
  v2f o = __builtin_nontemporal_load((const v2f*)out + oi);
  o.x += acc.x * r;
  o.y += acc.y * r;
  __builtin_nontemporal_store(o, (v2f*)out + oi);
}

extern "C" void kernel_launch(void* const* d_in, const int* in_sizes, int n_in,
                              void* d_out, int out_size, void* d_ws, size_t ws_size,
                              hipStream_t stream) {
  const float* x      = (const float*)d_in[0];
  const int*   ei     = (const int*)  d_in[1];
  const float* ea     = (const float*)d_in[2];
  const float* W_lin  = (const float*)d_in[3];
  const float* w_s    = (const float*)d_in[4];
  const float* b_s    = (const float*)d_in[5];
  const float* w_t    = (const float*)d_in[6];
  const float* b_t    = (const float*)d_in[7];
  const float* W_edge = (const float*)d_in[8];
  const float* w_e    = (const float*)d_in[9];
  const float* b_e    = (const float*)d_in[10];
  const float* W_res  = (const float*)d_in[11];
  const float* bias   = (const float*)d_in[12];
  int N_ = in_sizes[0] / IN_F;
  int E_ = in_sizes[1] / 2;
  float* out = (float*)d_out;

  // ws layout (~40.1 MB):
  // xp[N*128] f16 | pay[E] int4 | a_s[N*4] f32 | a_t[N*4] f32 | head[N*4]
  __half* xp    = (__half*)d_ws;
  v4i*    pay   = (v4i*)(xp + (size_t)N_ * HF);
  float*  a_s   = (float*)(pay + E_);
  float*  a_t   = a_s + (size_t)N_ * 4;
  int*    head  = (int*)(a_t + (size_t)N_ * 4);

  int PB = (N_ + 63) / 64;               // projection blocks (64 nodes each)
  int HB = (N_ * 4 + 255) / 256;         // head-init blocks

  k_project_mfma<<<PB + HB, 256, 0, stream>>>(
      x, W_lin, W_res, bias, w_s, w_t, b_s, b_t, xp, a_s, a_t, out, head, N_, PB);
  k_edge_logits<<<(E_ + 255) / 256, 256, 0, stream>>>(
      ei, ea, W_edge, w_e, b_e, a_s, a_t, head, pay, E_);
  k_gather<<<(N_ + 3) / 4, 256, 0, stream>>>(head, pay, xp, out, N_, E_);
}